// Round 1
// baseline (336.894 us; speedup 1.0000x reference)
//
#include <hip/hip_runtime.h>
#include <math.h>

#define BB 16
#define NN 4096
#define DD 64
#define OO 12
#define SS 32
#define MM 12
#define AA 32

// out layout: H_time [B,O,N,D] | attn [B,O,N,M] | gate [B,O,M]
__global__ __launch_bounds__(256) void stta_kernel(
    const float* __restrict__ H, const float* __restrict__ ts_out,
    const float* __restrict__ step_emb, const float* __restrict__ key_emb,
    const float* __restrict__ val_emb, const float* __restrict__ Wk,
    const float* __restrict__ Wg, const float* __restrict__ bgp,
    const float* __restrict__ Wq, const float* __restrict__ bq,
    float* __restrict__ out)
{
    const int b = blockIdx.y;
    const int n0 = blockIdx.x * 64;
    const int tid = threadIdx.x;

    __shared__ float s_wq[32 * 64];       // Wq[a][d], d<64
    __shared__ float s_ke[MM * AA];       // key_emb[m][a]
    __shared__ float s_ve[MM * DD];       // val_emb[m][d]
    __shared__ float s_wk0[32], s_wk1[32];
    __shared__ float s_tokS[OO * MM], s_tokC[OO * MM], s_gate[OO * MM];
    __shared__ float s_qs[OO * AA];       // qs[o][a]

    float* outH    = out;
    float* outAttn = out + (size_t)BB * OO * NN * DD;
    float* outGate = outAttn + (size_t)BB * OO * NN * MM;

    // ---- staging (one barrier) ----
    for (int i = tid; i < 32 * 64; i += 256) {
        int a = i >> 6, d = i & 63;
        s_wq[i] = Wq[a * 96 + d];
    }
    for (int i = tid; i < MM * AA; i += 256) s_ke[i] = key_emb[i];
    for (int i = tid; i < MM * DD; i += 256) s_ve[i] = val_emb[i];
    if (tid < 32) { s_wk0[tid] = Wk[tid * 2]; s_wk1[tid] = Wk[tid * 2 + 1]; }

    const float wg0 = Wg[0], wg1 = Wg[1], bg0 = bgp[0];
    for (int i = tid; i < OO * MM; i += 256) {
        int o = i / MM, m = i - o * MM;
        float phase = ts_out[(b * OO + o) * 2 + (m < 8 ? 0 : 1)];
        float k = (m < 8) ? (float)(m + 1) : (float)(m - 7);
        float ang = 6.283185307179586f * phase * k;
        float sv = sinf(ang), cv = cosf(ang);
        s_tokS[i] = sv; s_tokC[i] = cv;
        float gv = tanhf(sv * wg0 + cv * wg1 + bg0);
        s_gate[i] = gv;
        if (blockIdx.x == 0) outGate[(b * OO + o) * MM + m] = gv;
    }
    for (int e = tid; e < OO * AA; e += 256) {
        int o = e >> 5, a = e & 31;
        float acc = bq[a];
        const float* se = step_emb + (b * OO + o) * SS;
        const float* wq = Wq + a * 96 + 64;
        #pragma unroll
        for (int s = 0; s < SS; s++) acc += se[s] * wq[s];
        s_qs[e] = acc;
    }
    __syncthreads();

    const int nl = tid >> 2, g = tid & 3;
    const int n = n0 + nl;

    // ---- load my 16 H values (coalesced float4) ----
    const float4* h4p = reinterpret_cast<const float4*>(H + ((size_t)b * NN + n) * DD + g * 16);
    float4 h40 = h4p[0], h41 = h4p[1], h42 = h4p[2], h43 = h4p[3];
    float h[16] = { h40.x,h40.y,h40.z,h40.w, h41.x,h41.y,h41.z,h41.w,
                    h42.x,h42.y,h42.z,h42.w, h43.x,h43.y,h43.z,h43.w };

    // ---- partial qh over my 16 d's, all 32 a ----
    float qh[32];
    #pragma unroll
    for (int a = 0; a < 32; a++) {
        const float4* wq4 = reinterpret_cast<const float4*>(s_wq + a * 64 + g * 16);
        float4 w0 = wq4[0], w1 = wq4[1], w2 = wq4[2], w3 = wq4[3];
        float acc = h[0]*w0.x + h[1]*w0.y + h[2]*w0.z + h[3]*w0.w
                  + h[4]*w1.x + h[5]*w1.y + h[6]*w1.z + h[7]*w1.w
                  + h[8]*w2.x + h[9]*w2.y + h[10]*w2.z + h[11]*w2.w
                  + h[12]*w3.x + h[13]*w3.y + h[14]*w3.z + h[15]*w3.w;
        qh[a] = acc;
    }
    #pragma unroll
    for (int a = 0; a < 32; a++) qh[a] += __shfl_xor(qh[a], 1);
    #pragma unroll
    for (int a = 0; a < 32; a++) qh[a] += __shfl_xor(qh[a], 2);

    // extract my 8 a's (compile-time indices to keep everything in regs)
    float qm[8];
    if (g == 0) {
        #pragma unroll
        for (int i = 0; i < 8; i++) qm[i] = qh[i];
    } else if (g == 1) {
        #pragma unroll
        for (int i = 0; i < 8; i++) qm[i] = qh[8 + i];
    } else if (g == 2) {
        #pragma unroll
        for (int i = 0; i < 8; i++) qm[i] = qh[16 + i];
    } else {
        #pragma unroll
        for (int i = 0; i < 8; i++) qm[i] = qh[24 + i];
    }

    const float scale = 0.17677669529663687f; // 1/sqrt(32)
    const int a0 = g * 8;
    const float4* ve4 = reinterpret_cast<const float4*>(s_ve);

    for (int o = 0; o < OO; o++) {
        float q[8];
        #pragma unroll
        for (int i = 0; i < 8; i++) q[i] = qm[i] + s_qs[o * 32 + a0 + i];

        float u = 0.f, v = 0.f, w[12];
        #pragma unroll
        for (int i = 0; i < 8; i++) { u += q[i] * s_wk0[a0 + i]; v += q[i] * s_wk1[a0 + i]; }
        #pragma unroll
        for (int m = 0; m < 12; m++) {
            const float* ke = s_ke + m * 32 + a0;
            float acc = 0.f;
            #pragma unroll
            for (int i = 0; i < 8; i++) acc += q[i] * ke[i];
            w[m] = acc;
        }
        // reduce u,v,w over the 4-lane group
        u += __shfl_xor(u, 1); v += __shfl_xor(v, 1);
        #pragma unroll
        for (int m = 0; m < 12; m++) w[m] += __shfl_xor(w[m], 1);
        u += __shfl_xor(u, 2); v += __shfl_xor(v, 2);
        #pragma unroll
        for (int m = 0; m < 12; m++) w[m] += __shfl_xor(w[m], 2);

        // logits + softmax
        float lg[12], mx = -1e30f;
        #pragma unroll
        for (int m = 0; m < 12; m++) {
            lg[m] = (u * s_tokS[o * 12 + m] + v * s_tokC[o * 12 + m] + w[m]) * scale;
            mx = fmaxf(mx, lg[m]);
        }
        float sum = 0.f;
        #pragma unroll
        for (int m = 0; m < 12; m++) { lg[m] = expf(lg[m] - mx); sum += lg[m]; }
        float inv = 1.f / sum;

        // attn write: [B,O,N,M], 12 floats per n, lanes g=0..2 write float4 each
        size_t abase = ((size_t)(b * OO + o) * NN + n) * MM;
        if (g == 0) {
            *reinterpret_cast<float4*>(outAttn + abase) =
                make_float4(lg[0]*inv, lg[1]*inv, lg[2]*inv, lg[3]*inv);
        } else if (g == 1) {
            *reinterpret_cast<float4*>(outAttn + abase + 4) =
                make_float4(lg[4]*inv, lg[5]*inv, lg[6]*inv, lg[7]*inv);
        } else if (g == 2) {
            *reinterpret_cast<float4*>(outAttn + abase + 8) =
                make_float4(lg[8]*inv, lg[9]*inv, lg[10]*inv, lg[11]*inv);
        }

        // delta (gate folded into attn) + H_time write
        float ag[12];
        #pragma unroll
        for (int m = 0; m < 12; m++) ag[m] = lg[m] * inv * s_gate[o * 12 + m];

        size_t hbase = ((size_t)(b * OO + o) * NN + n) * DD + g * 16;
        float4* outp = reinterpret_cast<float4*>(outH + hbase);
        #pragma unroll
        for (int jj = 0; jj < 4; jj++) {
            float ax = 0.f, ay = 0.f, az = 0.f, aw = 0.f;
            #pragma unroll
            for (int m = 0; m < 12; m++) {
                float4 vv = ve4[m * 16 + g * 4 + jj];
                ax += ag[m] * vv.x; ay += ag[m] * vv.y;
                az += ag[m] * vv.z; aw += ag[m] * vv.w;
            }
            outp[jj] = make_float4(h[jj*4+0] + 0.1f*ax, h[jj*4+1] + 0.1f*ay,
                                   h[jj*4+2] + 0.1f*az, h[jj*4+3] + 0.1f*aw);
        }
    }
}

extern "C" void kernel_launch(void* const* d_in, const int* in_sizes, int n_in,
                              void* d_out, int out_size, void* d_ws, size_t ws_size,
                              hipStream_t stream) {
    const float* H        = (const float*)d_in[0];
    const float* ts_out   = (const float*)d_in[1];
    const float* step_emb = (const float*)d_in[2];
    const float* key_emb  = (const float*)d_in[3];
    const float* val_emb  = (const float*)d_in[4];
    const float* Wk       = (const float*)d_in[5];
    const float* Wg       = (const float*)d_in[6];
    const float* bg       = (const float*)d_in[7];
    const float* Wq       = (const float*)d_in[8];
    const float* bq       = (const float*)d_in[9];
    float* outp = (float*)d_out;

    dim3 grid(NN / 64, BB);
    stta_kernel<<<grid, 256, 0, stream>>>(H, ts_out, step_emb, key_emb, val_emb,
                                          Wk, Wg, bg, Wq, bq, outp);
}

// Round 2
// 293.183 us; speedup vs baseline: 1.1491x; 1.1491x over previous
//
#include <hip/hip_runtime.h>
#include <math.h>

#define BB 16
#define NN 4096
#define DD 64
#define OO 12
#define SS 32
#define MM 12
#define AA 32

// out layout: H_time [B,O,N,D] | attn [B,O,N,M] | gate [B,O,M]
__global__ __launch_bounds__(256, 4) void stta_kernel(
    const float* __restrict__ H, const float* __restrict__ ts_out,
    const float* __restrict__ step_emb, const float* __restrict__ key_emb,
    const float* __restrict__ val_emb, const float* __restrict__ Wk,
    const float* __restrict__ Wg, const float* __restrict__ bgp,
    const float* __restrict__ Wq, const float* __restrict__ bq,
    float* __restrict__ out)
{
    const int b = blockIdx.y;
    const int n0 = blockIdx.x * 64;
    const int tid = threadIdx.x;

    __shared__ float s_wq[32 * 64];       // Wq[a][d], d<64
    __shared__ float s_ke[MM * AA];       // key_emb[m][a]
    __shared__ float s_ve[MM * DD];       // val_emb[m][d]
    __shared__ float s_wk0[32], s_wk1[32];
    __shared__ float s_tokS[OO * MM], s_tokC[OO * MM], s_gate[OO * MM];
    __shared__ float s_qs[OO * AA];       // qs[o][a]
    __shared__ float s_c2[OO * MM];       // scale * (qs[o] . key[o,m])

    float* outH    = out;
    float* outAttn = out + (size_t)BB * OO * NN * DD;
    float* outGate = outAttn + (size_t)BB * OO * NN * MM;

    const float scale = 0.17677669529663687f; // 1/sqrt(32)

    // ---- staging ----
    for (int i = tid; i < 32 * 64; i += 256) {
        int a = i >> 6, d = i & 63;
        s_wq[i] = Wq[a * 96 + d];
    }
    for (int i = tid; i < MM * AA; i += 256) s_ke[i] = key_emb[i];
    for (int i = tid; i < MM * DD; i += 256) s_ve[i] = val_emb[i];
    if (tid < 32) { s_wk0[tid] = Wk[tid * 2]; s_wk1[tid] = Wk[tid * 2 + 1]; }

    const float wg0 = Wg[0], wg1 = Wg[1], bg0 = bgp[0];
    for (int i = tid; i < OO * MM; i += 256) {
        int o = i / MM, m = i - o * MM;
        float phase = ts_out[(b * OO + o) * 2 + (m < 8 ? 0 : 1)];
        float k = (m < 8) ? (float)(m + 1) : (float)(m - 7);
        float ang = 6.283185307179586f * phase * k;
        float sv = sinf(ang), cv = cosf(ang);
        s_tokS[i] = sv; s_tokC[i] = cv;
        float gv = tanhf(sv * wg0 + cv * wg1 + bg0);
        s_gate[i] = gv;
        if (blockIdx.x == 0) outGate[(b * OO + o) * MM + m] = gv;
    }
    for (int e = tid; e < OO * AA; e += 256) {
        int o = e >> 5, a = e & 31;
        float acc = bq[a];
        const float* se = step_emb + (b * OO + o) * SS;
        const float* wq = Wq + a * 96 + 64;
        #pragma unroll
        for (int s = 0; s < SS; s++) acc += se[s] * wq[s];
        s_qs[e] = acc;
    }
    __syncthreads();

    // ---- c2[o][m] = scale * (qs[o] . key[o,m]) ----
    for (int i = tid; i < OO * MM; i += 256) {
        int o = i / MM, m = i - o * MM;
        float S = s_tokS[i], C = s_tokC[i];
        float acc = 0.f;
        const float* qs = s_qs + o * 32;
        const float* ke = s_ke + m * 32;
        #pragma unroll
        for (int a = 0; a < 32; a++)
            acc += qs[a] * (S * s_wk0[a] + C * s_wk1[a] + ke[a]);
        s_c2[i] = acc * scale;
    }
    __syncthreads();

    const int nl = tid >> 2, g = tid & 3;
    const int n = n0 + nl;

    // ---- load my 16 H values (coalesced float4) ----
    const float4* h4p = reinterpret_cast<const float4*>(H + ((size_t)b * NN + n) * DD + g * 16);
    float4 h40 = h4p[0], h41 = h4p[1], h42 = h4p[2], h43 = h4p[3];
    float h[16] = { h40.x,h40.y,h40.z,h40.w, h41.x,h41.y,h41.z,h41.w,
                    h42.x,h42.y,h42.z,h42.w, h43.x,h43.y,h43.z,h43.w };

    // ---- qh: partial over my 16 d's for all 32 a, butterfly over 4-lane group
    //      (butterfly leaves the FULL sum in every lane) ----
    float uh = 0.f, vh = 0.f;
    float wh[12] = {0,0,0,0,0,0,0,0,0,0,0,0};
    {
        float qh[32];
        #pragma unroll
        for (int a = 0; a < 32; a++) {
            const float4* wq4 = reinterpret_cast<const float4*>(s_wq + a * 64 + g * 16);
            float4 w0 = wq4[0], w1 = wq4[1], w2 = wq4[2], w3 = wq4[3];
            qh[a] = h[0]*w0.x + h[1]*w0.y + h[2]*w0.z + h[3]*w0.w
                  + h[4]*w1.x + h[5]*w1.y + h[6]*w1.z + h[7]*w1.w
                  + h[8]*w2.x + h[9]*w2.y + h[10]*w2.z + h[11]*w2.w
                  + h[12]*w3.x + h[13]*w3.y + h[14]*w3.z + h[15]*w3.w;
        }
        #pragma unroll
        for (int a = 0; a < 32; a++) qh[a] += __shfl_xor(qh[a], 1);
        #pragma unroll
        for (int a = 0; a < 32; a++) qh[a] += __shfl_xor(qh[a], 2);

        // uh, vh, wh[12] — logits are linear in qh; precompute projections once
        #pragma unroll
        for (int a = 0; a < 32; a++) { uh += qh[a] * s_wk0[a]; vh += qh[a] * s_wk1[a]; }
        #pragma unroll
        for (int m = 0; m < 12; m++) {
            const float* ke = s_ke + m * 32;
            float acc = 0.f;
            #pragma unroll
            for (int a = 0; a < 32; a++) acc += qh[a] * ke[a];
            wh[m] = acc * scale;
        }
        uh *= scale; vh *= scale;
    }

    const float4* ve4 = reinterpret_cast<const float4*>(s_ve);

    for (int o = 0; o < OO; o++) {
        // logits: 2 FMA + 1 add per m — no shuffles, no dot products
        float lg[12], mx = -1e30f;
        #pragma unroll
        for (int m = 0; m < 12; m++) {
            int i = o * 12 + m;
            lg[m] = s_tokS[i] * uh + s_tokC[i] * vh + wh[m] + s_c2[i];
            mx = fmaxf(mx, lg[m]);
        }
        float sum = 0.f;
        #pragma unroll
        for (int m = 0; m < 12; m++) { lg[m] = __expf(lg[m] - mx); sum += lg[m]; }
        float inv = 1.f / sum;

        // attn write: [B,O,N,M], lanes g=0..2 write float4 each
        size_t abase = ((size_t)(b * OO + o) * NN + n) * MM;
        if (g == 0) {
            *reinterpret_cast<float4*>(outAttn + abase) =
                make_float4(lg[0]*inv, lg[1]*inv, lg[2]*inv, lg[3]*inv);
        } else if (g == 1) {
            *reinterpret_cast<float4*>(outAttn + abase + 4) =
                make_float4(lg[4]*inv, lg[5]*inv, lg[6]*inv, lg[7]*inv);
        } else if (g == 2) {
            *reinterpret_cast<float4*>(outAttn + abase + 8) =
                make_float4(lg[8]*inv, lg[9]*inv, lg[10]*inv, lg[11]*inv);
        }

        // delta (gate folded into attn) + H_time write
        float ag[12];
        #pragma unroll
        for (int m = 0; m < 12; m++) ag[m] = lg[m] * inv * s_gate[o * 12 + m];

        size_t hbase = ((size_t)(b * OO + o) * NN + n) * DD + g * 16;
        float4* outp = reinterpret_cast<float4*>(outH + hbase);
        #pragma unroll
        for (int jj = 0; jj < 4; jj++) {
            float ax = 0.f, ay = 0.f, az = 0.f, aw = 0.f;
            #pragma unroll
            for (int m = 0; m < 12; m++) {
                float4 vv = ve4[m * 16 + g * 4 + jj];
                ax += ag[m] * vv.x; ay += ag[m] * vv.y;
                az += ag[m] * vv.z; aw += ag[m] * vv.w;
            }
            outp[jj] = make_float4(h[jj*4+0] + 0.1f*ax, h[jj*4+1] + 0.1f*ay,
                                   h[jj*4+2] + 0.1f*az, h[jj*4+3] + 0.1f*aw);
        }
    }
}

extern "C" void kernel_launch(void* const* d_in, const int* in_sizes, int n_in,
                              void* d_out, int out_size, void* d_ws, size_t ws_size,
                              hipStream_t stream) {
    const float* H        = (const float*)d_in[0];
    const float* ts_out   = (const float*)d_in[1];
    const float* step_emb = (const float*)d_in[2];
    const float* key_emb  = (const float*)d_in[3];
    const float* val_emb  = (const float*)d_in[4];
    const float* Wk       = (const float*)d_in[5];
    const float* Wg       = (const float*)d_in[6];
    const float* bg       = (const float*)d_in[7];
    const float* Wq       = (const float*)d_in[8];
    const float* bq       = (const float*)d_in[9];
    float* outp = (float*)d_out;

    dim3 grid(NN / 64, BB);
    stta_kernel<<<grid, 256, 0, stream>>>(H, ts_out, step_emb, key_emb, val_emb,
                                          Wk, Wg, bg, Wq, bq, outp);
}